// Round 4
// baseline (1945.140 us; speedup 1.0000x reference)
//
#include <hip/hip_runtime.h>
#include <cfloat>
#include <math.h>

// Problem constants
#define BQ 8
#define T 2048
#define D 256
#define DAC 36
#define CH 292
#define K 8192
#define NROWS (BQ*T)          // 16384
#define TAU 2e-4f

// Output offsets (floats, reference return order)
#define OFF_IDX   (BQ*CH*T)
#define OFF_CODES (OFF_IDX + NROWS)
#define OFF_LOSS  (OFF_CODES + BQ*DAC*T)
#define OFF_ACQ   (OFF_LOSS + 1)

// ---------------- new (MFMA) ws layout, bytes ----------------
#define WN_C2    0
#define WN_Z2    32768
#define WN_CNT   98304
#define WN_LIST  98560
#define WN_LOSS  164096
#define WN_WIDX  168192
#define WN_PM1   262144
#define WN_PM2   (WN_PM1 + 4194304)
#define WN_PIDX  (WN_PM2 + 4194304)
#define WN_AZ    (WN_PIDX + 4194304)          // ushort[16384][512]
#define WN_BC    (WN_AZ + 16777216)           // ushort[8192][512]
#define WN_NEED  (WN_BC + 8388608)            // 38,010,880 B

// ---------------- old (fallback) ws layout ----------------
#define WS_C2    0
#define WS_Z2    32768
#define WS_PART  131072
#define WS_IDX   655360
#define WS_LOSS  720896
#define MT 32
#define KT 128
#define DC 32
#define NSPLIT 4

typedef float f32x4 __attribute__((ext_vector_type(4)));
typedef __bf16 bf16x8 __attribute__((ext_vector_type(8)));
typedef __attribute__((address_space(1))) const unsigned int gu32;
typedef __attribute__((address_space(3))) unsigned int lu32;

__device__ inline void gl_lds16(const void* gp, void* lp) {
    __builtin_amdgcn_global_load_lds((gu32*)gp, (lu32*)lp, 16, 0, 0);
}

__device__ inline unsigned short f2bf(float x) {   // RNE, finite inputs
    unsigned u = __float_as_uint(x);
    return (unsigned short)((u + 0x7fffu + ((u >> 16) & 1u)) >> 16);
}
__device__ inline float bf2f(unsigned short h) {
    return __uint_as_float(((unsigned)h) << 16);
}

__device__ inline void merge3(float& m1, float& m2, int& mi, float o1, float o2, int oi) {
    if (o1 < m1 || (o1 == m1 && oi < mi)) { m2 = fminf(m1, o2); m1 = o1; mi = oi; }
    else                                  { m2 = fminf(m2, o1); }
}

// ---- numpy pairwise-sum emulation (AVX512 W=16, n=256) ----
template <typename F>
__device__ float np_pairwise256_sq(F ld) {
    float S[2];
    #pragma unroll
    for (int h = 0; h < 2; h++) {
        int base = h * 128;
        float v[16];
        #pragma unroll
        for (int l = 0; l < 16; l++) {
            float q[8];
            #pragma unroll
            for (int j = 0; j < 8; j++) { float x = ld(base + j * 16 + l); q[j] = x * x; }
            v[l] = ((q[0] + q[1]) + (q[2] + q[3])) + ((q[4] + q[5]) + (q[6] + q[7]));
        }
        float t1[8], t2[4], t3[2];
        #pragma unroll
        for (int l = 0; l < 8; l++) t1[l] = v[l] + v[l + 8];
        #pragma unroll
        for (int l = 0; l < 4; l++) t2[l] = t1[l] + t1[l + 4];
        t3[0] = t2[0] + t2[2]; t3[1] = t2[1] + t2[3];
        S[h] = t3[0] + t3[1];
    }
    return S[0] + S[1];
}

__global__ void k_c2pw(const float* __restrict__ cb, float* __restrict__ c2) {
    int k = blockIdx.x * 256 + threadIdx.x;
    const float* row = cb + (size_t)k * D;
    c2[k] = np_pairwise256_sq([&](int d) { return row[d]; });
}

__global__ void k_z2pw(const float* __restrict__ z, float* __restrict__ z2) {
    int n = blockIdx.x * 256 + threadIdx.x;
    int b = n >> 11, t = n & 2047;
    const float* base = z + (size_t)b * CH * T + t;
    z2[n] = np_pairwise256_sq([&](int d) { return base[(size_t)d * T]; });
}

// ---------------- prep: Az[n][512] = [bf16hi(z) | bf16lo(z)] ----------------
__global__ __launch_bounds__(256) void k_prepz(const float* __restrict__ z,
                                               unsigned short* __restrict__ Az) {
    __shared__ float zt[32][260];
    const int tid = threadIdx.x;
    const int b = blockIdx.x >> 6, t0 = (blockIdx.x & 63) * 32;
    for (int i = tid; i < 2048; i += 256) {
        int d = i >> 3, tq = (i & 7) * 4;
        float4 v = *(const float4*)(z + (size_t)(b * CH + d) * T + t0 + tq);
        zt[tq + 0][d] = v.x; zt[tq + 1][d] = v.y;
        zt[tq + 2][d] = v.z; zt[tq + 3][d] = v.w;
    }
    __syncthreads();
    const int t = tid >> 3, c8 = tid & 7;
    unsigned short* rowp = Az + (size_t)(b * 2048 + t0 + t) * 512;
    #pragma unroll
    for (int li = 0; li < 8; li++) {
        int u = c8 + 8 * li;                 // 16B chunk index 0..63
        int dbase = (u & 31) * 8;
        bool lo = (u >= 32);
        float f[8];
        *(float4*)&f[0] = *(float4*)&zt[t][dbase];
        *(float4*)&f[4] = *(float4*)&zt[t][dbase + 4];
        unsigned short h[8];
        #pragma unroll
        for (int e = 0; e < 8; e++) {
            unsigned short hh = f2bf(f[e]);
            h[e] = lo ? f2bf(f[e] - bf2f(hh)) : hh;
        }
        *(uint4*)(rowp + u * 8) = *(uint4*)h;
    }
}

// ---------------- prep: Bc[k][512] = [bf16hi(c) | bf16lo(c)] ----------------
__global__ void k_prepc(const float* __restrict__ cb, unsigned short* __restrict__ Bc) {
    const int tid = threadIdx.x, w = tid >> 6, l = tid & 63;
    const int k = blockIdx.x * 4 + w;
    float4 v = *(const float4*)(cb + (size_t)k * D + l * 4);
    float fa[4] = {v.x, v.y, v.z, v.w};
    unsigned short hi[4], lo[4];
    #pragma unroll
    for (int e = 0; e < 4; e++) {
        hi[e] = f2bf(fa[e]);
        lo[e] = f2bf(fa[e] - bf2f(hi[e]));
    }
    unsigned short* rowp = Bc + (size_t)k * 512;
    *(uint2*)(rowp + l * 4)       = *(uint2*)hi;
    *(uint2*)(rowp + 256 + l * 4) = *(uint2*)lo;
}

// ---------------- MFMA fast argmin: 128x128 tile, Keff=768 (3-term split) ----
// score = c2[k] - 2*dot;  track (m1, m2, idx) per row; partials per k-tile.
__global__ __launch_bounds__(256) void k_fast(
        const unsigned short* __restrict__ Az, const unsigned short* __restrict__ Bc,
        const float* __restrict__ c2g, float* __restrict__ pm1,
        float* __restrict__ pm2, int* __restrict__ pidx) {
    __shared__ unsigned char smem8[32768];   // As 16KB | Bs 16KB
    __shared__ float redm1[128], redm2[128];
    __shared__ int   redi[128];

    const int tid = threadIdx.x;
    const int w = tid >> 6, lane = tid & 63;
    const int wm = w >> 1, wn = w & 1;
    const int quad = lane >> 4, c = lane & 15, c7 = c & 7;

    // supertile swizzle: 8 nt x 8 kt blocks share ~2MB working set
    const int st = blockIdx.x >> 6, lx = blockIdx.x & 63;
    const int nt = (st >> 3) * 8 + (lx >> 3);
    const int kt = (st & 7) * 8 + (lx & 7);
    const int n0 = nt * 128, k0 = kt * 128;

    // staging lane geometry (global-side XOR swizzle; LDS dest is lane-forced)
    const int srow = lane >> 3;
    const int gsw = (lane & 7) ^ (srow & 7);

    f32x4 acc[4][4];
    #pragma unroll
    for (int i = 0; i < 4; i++)
        #pragma unroll
        for (int j = 0; j < 4; j++) acc[i][j] = (f32x4)0.0f;

    int aoff[4], boff[4];
    #pragma unroll
    for (int i = 0; i < 4; i++) aoff[i] = (wm * 64 + i * 16 + c) * 128;
    #pragma unroll
    for (int j = 0; j < 4; j++) boff[j] = 16384 + (wn * 64 + j * 16 + c) * 128;

    for (int it = 0; it < 12; ++it) {
        const int blk = it >> 2, cb64 = (it & 3) * 128;   // bytes in 256-col block
        const int colA = ((blk == 1) ? 512 : 0) + cb64;   // A: [zh | zl], zh again for blk2
        const int colB = ((blk == 2) ? 512 : 0) + cb64;   // B: [ch | cl]
        __syncthreads();
        #pragma unroll
        for (int q = 0; q < 4; q++) {
            const int seg = w * 4 + q;
            gl_lds16((const char*)Az + (size_t)(n0 + seg * 8 + srow) * 1024 + colA + gsw * 16,
                     smem8 + seg * 1024);
            gl_lds16((const char*)Bc + (size_t)(k0 + seg * 8 + srow) * 1024 + colB + gsw * 16,
                     smem8 + 16384 + seg * 1024);
        }
        __syncthreads();
        #pragma unroll
        for (int s = 0; s < 2; s++) {
            const int sw = ((((s << 2) | quad) ^ c7) << 4);
            bf16x8 af[4], bfr[4];
            #pragma unroll
            for (int i = 0; i < 4; i++) af[i] = *(const bf16x8*)(smem8 + aoff[i] + sw);
            #pragma unroll
            for (int j = 0; j < 4; j++) bfr[j] = *(const bf16x8*)(smem8 + boff[j] + sw);
            #pragma unroll
            for (int i = 0; i < 4; i++)
                #pragma unroll
                for (int j = 0; j < 4; j++)
                    acc[i][j] = __builtin_amdgcn_mfma_f32_16x16x32_bf16(af[i], bfr[j], acc[i][j], 0, 0, 0);
        }
    }

    // scores + per-lane (m1,m2,idx) for 16 rows (i,reg), 4 codes (j)
    float bm1[16], bm2[16]; int bid[16];
    #pragma unroll
    for (int sl = 0; sl < 16; sl++) { bm1[sl] = FLT_MAX; bm2[sl] = FLT_MAX; bid[sl] = 0x7fffffff; }
    #pragma unroll
    for (int j = 0; j < 4; j++) {
        const int kk = k0 + wn * 64 + j * 16 + c;
        const float c2v = c2g[kk];
        #pragma unroll
        for (int i = 0; i < 4; i++)
            #pragma unroll
            for (int r = 0; r < 4; r++) {
                float s = fmaf(-2.0f, acc[i][j][r], c2v);
                int sl = i * 4 + r;
                if (s < bm1[sl]) { bm2[sl] = bm1[sl]; bm1[sl] = s; bid[sl] = kk; }
                else if (s < bm2[sl]) bm2[sl] = s;
            }
    }
    // butterfly over the 16 c-lanes (same quad)
    #pragma unroll
    for (int mask = 1; mask <= 8; mask <<= 1)
        #pragma unroll
        for (int sl = 0; sl < 16; sl++) {
            float o1 = __shfl_xor(bm1[sl], mask, 64);
            float o2 = __shfl_xor(bm2[sl], mask, 64);
            int   oi = __shfl_xor(bid[sl], mask, 64);
            merge3(bm1[sl], bm2[sl], bid[sl], o1, o2, oi);
        }
    if (c == 0 && wn == 0) {
        #pragma unroll
        for (int i = 0; i < 4; i++)
            #pragma unroll
            for (int r = 0; r < 4; r++) {
                int ml = wm * 64 + i * 16 + quad * 4 + r, sl = i * 4 + r;
                redm1[ml] = bm1[sl]; redm2[ml] = bm2[sl]; redi[ml] = bid[sl];
            }
    }
    __syncthreads();
    if (c == 0 && wn == 1) {
        #pragma unroll
        for (int i = 0; i < 4; i++)
            #pragma unroll
            for (int r = 0; r < 4; r++) {
                int ml = wm * 64 + i * 16 + quad * 4 + r, sl = i * 4 + r;
                merge3(bm1[sl], bm2[sl], bid[sl], redm1[ml], redm2[ml], redi[ml]);
                size_t p = (size_t)kt * NROWS + n0 + ml;
                pm1[p] = bm1[sl]; pm2[p] = bm2[sl]; pidx[p] = bid[sl];
            }
    }
}

// ---------------- reduce 64 k-splits; flag ambiguous rows ----------------
__global__ void k_reduce2(const float* __restrict__ pm1, const float* __restrict__ pm2,
                          const int* __restrict__ pidx, int* __restrict__ widx,
                          int* __restrict__ cnt, int* __restrict__ list,
                          float* __restrict__ out) {
    int n = blockIdx.x * 256 + threadIdx.x;
    float a1 = FLT_MAX, a2 = FLT_MAX; int ai = 0x7fffffff;
    for (int s = 0; s < 64; s++) {
        size_t p = (size_t)s * NROWS + n;
        merge3(a1, a2, ai, pm1[p], pm2[p], pidx[p]);
    }
    widx[n] = ai;
    out[OFF_IDX + n] = (float)ai;
    if (a2 - a1 < TAU) { int pos = atomicAdd(cnt, 1); list[pos] = n; }
}

// ---------------- exact np-pipeline rescue for flagged rows ----------------
__global__ __launch_bounds__(256) void k_rescue2(
        const float* __restrict__ z, const float* __restrict__ cb,
        const float* __restrict__ c2, const float* __restrict__ z2,
        const int* __restrict__ cnt, const int* __restrict__ list,
        int* __restrict__ widx, float* __restrict__ out) {
    __shared__ float zrow[D];
    __shared__ float rv[256];
    __shared__ int   ri[256];
    __shared__ int   srown;
    const int tid = threadIdx.x;
    const int cntv = *cnt;
    for (int i = blockIdx.x; i < cntv; i += 64) {
        if (tid == 0) srown = list[i];
        __syncthreads();
        const int n = srown;
        const int bb = n >> 11, tt = n & 2047;
        zrow[tid] = z[(size_t)(bb * CH + tid) * T + tt];
        const float z2n = z2[n];
        __syncthreads();
        float bm = FLT_MAX; int bi = 0x7fffffff;
        #pragma unroll 2
        for (int j = 0; j < 32; j++) {           // k = tid + 256*j, ascending
            const int k = tid + 256 * j;
            const float4* cr = (const float4*)(cb + (size_t)k * D);
            float e = 0.f;
            #pragma unroll 16
            for (int d4 = 0; d4 < 64; d4++) {
                float4 cv = cr[d4];
                e = fmaf(zrow[d4 * 4 + 0], cv.x, e);
                e = fmaf(zrow[d4 * 4 + 1], cv.y, e);
                e = fmaf(zrow[d4 * 4 + 2], cv.z, e);
                e = fmaf(zrow[d4 * 4 + 3], cv.w, e);
            }
            float s = (z2n - 2.0f * e) + c2[k];
            if (s < bm) { bm = s; bi = k; }
        }
        rv[tid] = bm; ri[tid] = bi;
        __syncthreads();
        for (int s = 128; s > 0; s >>= 1) {
            if (tid < s) {
                float ov = rv[tid + s]; int oi = ri[tid + s];
                if (ov < rv[tid] || (ov == rv[tid] && oi < ri[tid])) { rv[tid] = ov; ri[tid] = oi; }
            }
            __syncthreads();
        }
        if (tid == 0) { widx[n] = ri[0]; out[OFF_IDX + n] = (float)ri[0]; }
        __syncthreads();
    }
}

// ---------------- fallback exact fp32 GEMM-argmin (Round-3, passing) --------
__global__ __launch_bounds__(256) void k_exact(
        const float* __restrict__ z, const float* __restrict__ cb,
        const float* __restrict__ c2, const float* __restrict__ z2,
        float2* __restrict__ part) {
    __shared__ float zs[D][MT];
    __shared__ float cs[DC][KT + 4];
    const int tid = threadIdx.x;
    const int tx = tid & 31, ty = tid >> 5;
    const int n0 = blockIdx.x * MT;
    const int bb = n0 >> 11, t0 = n0 & 2047;
    const int kbase = blockIdx.y * (K / NSPLIT);
    for (int i = tid; i < D * (MT / 4); i += 256) {
        int d = i >> 3, tg = i & 7;
        float4 v = *(const float4*)(z + ((size_t)(bb * CH + d)) * T + t0 + tg * 4);
        *(float4*)&zs[d][tg * 4] = v;
    }
    float z2r[4];
    #pragma unroll
    for (int i = 0; i < 4; i++) z2r[i] = z2[n0 + ty * 4 + i];
    float m1[4]; int bi[4];
    #pragma unroll
    for (int i = 0; i < 4; i++) { m1[i] = FLT_MAX; bi[i] = 0x7fffffff; }
    for (int ktt = 0; ktt < K / NSPLIT; ktt += KT) {
        const int k0 = kbase + ktt;
        float acc[4][4] = {};
        for (int dc = 0; dc < D; dc += DC) {
            __syncthreads();
            {
                int kl = tid & 127, half = tid >> 7;
                const float4* src = (const float4*)(cb + (size_t)(k0 + kl) * D + dc + half * 16);
                #pragma unroll
                for (int j = 0; j < 4; j++) {
                    float4 v = src[j];
                    int dl = half * 16 + j * 4;
                    cs[dl + 0][kl] = v.x; cs[dl + 1][kl] = v.y;
                    cs[dl + 2][kl] = v.z; cs[dl + 3][kl] = v.w;
                }
            }
            __syncthreads();
            #pragma unroll 8
            for (int d = 0; d < DC; d++) {
                const float4 zf = *(const float4*)&zs[dc + d][ty * 4];
                const float4 cf = *(const float4*)&cs[d][tx * 4];
                const float za[4] = {zf.x, zf.y, zf.z, zf.w};
                const float ca[4] = {cf.x, cf.y, cf.z, cf.w};
                #pragma unroll
                for (int i = 0; i < 4; i++)
                    #pragma unroll
                    for (int j = 0; j < 4; j++)
                        acc[i][j] = fmaf(za[i], ca[j], acc[i][j]);
            }
        }
        #pragma unroll
        for (int j = 0; j < 4; j++) {
            int kk = k0 + tx * 4 + j;
            float c2v = c2[kk];
            #pragma unroll
            for (int i = 0; i < 4; i++) {
                float tpre = z2r[i] - 2.0f * acc[i][j];
                float s = tpre + c2v;
                if (s < m1[i]) { m1[i] = s; bi[i] = kk; }
            }
        }
    }
    __syncthreads();
    float* rm1 = (float*)zs;
    int*   rix = (int*)(rm1 + MT * 32);
    #pragma unroll
    for (int i = 0; i < 4; i++) {
        int slot = (ty * 4 + i) * 32 + tx;
        rm1[slot] = m1[i]; rix[slot] = bi[i];
    }
    __syncthreads();
    if (tid < MT) {
        float a1 = FLT_MAX; int ai = 0x7fffffff;
        for (int t = 0; t < 32; t++) {
            float b1 = rm1[tid * 32 + t]; int bidx = rix[tid * 32 + t];
            if (b1 < a1 || (b1 == a1 && bidx < ai)) { a1 = b1; ai = bidx; }
        }
        part[(size_t)(n0 + tid) * NSPLIT + blockIdx.y] = make_float2(a1, __int_as_float(ai));
    }
}

__global__ void k_reduce(const float2* __restrict__ part, int* __restrict__ widx,
                         float* __restrict__ out) {
    int n = blockIdx.x * 256 + threadIdx.x;
    float a1 = FLT_MAX; int ai = 0x7fffffff;
    #pragma unroll
    for (int s = 0; s < NSPLIT; s++) {
        float2 p = part[(size_t)n * NSPLIT + s];
        float b1 = p.x; int bidx = __float_as_int(p.y);
        if (b1 < a1 || (b1 == a1 && bidx < ai)) { a1 = b1; ai = bidx; }
    }
    widx[n] = ai;
    out[OFF_IDX + n] = (float)ai;
}

// ------------- epilogue: gather z_q + loss partials ----------------
__global__ __launch_bounds__(256) void k_episem(
        const float* __restrict__ z, const float* __restrict__ cb,
        const int* __restrict__ widx, float* __restrict__ out, double* __restrict__ lossp) {
    __shared__ int qidx[32];
    __shared__ float qs[32][260];
    __shared__ double wsum[4];
    const int tid = threadIdx.x;
    const int bb = blockIdx.x >> 6;
    const int t0 = (blockIdx.x & 63) * 32;
    if (tid < 32) qidx[tid] = widx[bb * T + t0 + tid];
    __syncthreads();
    for (int i = tid; i < 32 * 64; i += 256) {
        int tl = i >> 6, lanee = i & 63;
        float4 v = *(const float4*)(cb + (size_t)qidx[tl] * D + lanee * 4);
        *(float4*)&qs[tl][lanee * 4] = v;
    }
    __syncthreads();
    double ls = 0.0;
    for (int it = 0; it < 32; it++) {
        int d = it * 8 + (tid >> 5);
        int tl = tid & 31;
        size_t ga = ((size_t)(bb * CH + d)) * T + t0 + tl;
        float q = qs[tl][d];
        float e = q - z[ga];
        out[ga] = q;
        ls += (double)e * (double)e;
    }
    #pragma unroll
    for (int off = 32; off; off >>= 1) ls += __shfl_down(ls, off, 64);
    if ((tid & 63) == 0) wsum[tid >> 6] = ls;
    __syncthreads();
    if (tid == 0) lossp[blockIdx.x] = wsum[0] + wsum[1] + wsum[2] + wsum[3];
}

// ------------- epilogue: ac path ----------------
__global__ void k_epiac(const float* __restrict__ z, float* __restrict__ out) {
    int i = (blockIdx.x * 256 + threadIdx.x) * 4;
    if (i >= BQ * DAC * T) return;
    int b = i / (DAC * T);
    int r = i % (DAC * T);
    int d = r / T, t = r % T;
    size_t zoff = ((size_t)(b * CH + 256 + d)) * T + t;
    float4 v = *(const float4*)(z + zoff);
    float r0, r1, r2, r3;
    {
        float t0 = (float)tanh((double)v.x); r0 = rintf(t0 * 10.0f);
        float t1 = (float)tanh((double)v.y); r1 = rintf(t1 * 10.0f);
        float t2 = (float)tanh((double)v.z); r2 = rintf(t2 * 10.0f);
        float t3 = (float)tanh((double)v.w); r3 = rintf(t3 * 10.0f);
    }
    *(float4*)(out + zoff) = make_float4(r0, r1, r2, r3);
    size_t co = OFF_CODES + (size_t)(b * DAC + d) * T + t;
    *(float4*)(out + co) = make_float4(r0 + 10.0f, r1 + 10.0f, r2 + 10.0f, r3 + 10.0f);
    size_t ao = OFF_ACQ + (size_t)(b * DAC + d) * T + t;
    out[ao + 0] = r0; out[ao + 1] = r1; out[ao + 2] = r2; out[ao + 3] = r3;
}

__global__ void k_lossfin(const double* __restrict__ lossp, float* __restrict__ out) {
    __shared__ double sm[256];
    int tid = threadIdx.x;
    sm[tid] = lossp[tid] + lossp[tid + 256];
    __syncthreads();
    for (int off = 128; off; off >>= 1) {
        if (tid < off) sm[tid] += sm[tid + off];
        __syncthreads();
    }
    if (tid == 0) out[OFF_LOSS] = (float)(1.1 * sm[0] / (double)(BQ * D * T));
}

extern "C" void kernel_launch(void* const* d_in, const int* in_sizes, int n_in,
                              void* d_out, int out_size, void* d_ws, size_t ws_size,
                              hipStream_t stream) {
    const float* z  = (const float*)d_in[0];
    const float* cb = (const float*)d_in[1];
    float* out = (float*)d_out;
    char* ws = (char*)d_ws;

    if (ws_size >= (size_t)WN_NEED) {
        float*  c2    = (float*)(ws + WN_C2);
        float*  z2    = (float*)(ws + WN_Z2);
        int*    cnt   = (int*)(ws + WN_CNT);
        int*    list  = (int*)(ws + WN_LIST);
        double* lossp = (double*)(ws + WN_LOSS);
        int*    widx  = (int*)(ws + WN_WIDX);
        float*  pm1   = (float*)(ws + WN_PM1);
        float*  pm2   = (float*)(ws + WN_PM2);
        int*    pidx  = (int*)(ws + WN_PIDX);
        unsigned short* Az = (unsigned short*)(ws + WN_AZ);
        unsigned short* Bc = (unsigned short*)(ws + WN_BC);

        hipLaunchKernelGGL(k_prepc,   dim3(K / 4),       dim3(256), 0, stream, cb, Bc);
        hipLaunchKernelGGL(k_prepz,   dim3(512),         dim3(256), 0, stream, z, Az);
        hipLaunchKernelGGL(k_c2pw,    dim3(K / 256),     dim3(256), 0, stream, cb, c2);
        hipLaunchKernelGGL(k_z2pw,    dim3(NROWS / 256), dim3(256), 0, stream, z, z2);
        hipMemsetAsync(cnt, 0, 4, stream);
        hipLaunchKernelGGL(k_fast,    dim3(8192),        dim3(256), 0, stream, Az, Bc, c2, pm1, pm2, pidx);
        hipLaunchKernelGGL(k_reduce2, dim3(NROWS / 256), dim3(256), 0, stream, pm1, pm2, pidx, widx, cnt, list, out);
        hipLaunchKernelGGL(k_rescue2, dim3(64),          dim3(256), 0, stream, z, cb, c2, z2, cnt, list, widx, out);
        hipLaunchKernelGGL(k_episem,  dim3(BQ * (T / 32)), dim3(256), 0, stream, z, cb, widx, out, lossp);
        hipLaunchKernelGGL(k_epiac,   dim3(BQ * DAC * T / 1024), dim3(256), 0, stream, z, out);
        hipLaunchKernelGGL(k_lossfin, dim3(1),           dim3(256), 0, stream, lossp, out);
    } else {
        float*  c2    = (float*)(ws + WS_C2);
        float*  z2    = (float*)(ws + WS_Z2);
        float2* part  = (float2*)(ws + WS_PART);
        int*    widx  = (int*)(ws + WS_IDX);
        double* lossp = (double*)(ws + WS_LOSS);
        hipLaunchKernelGGL(k_c2pw,   dim3(K / 256),            dim3(256), 0, stream, cb, c2);
        hipLaunchKernelGGL(k_z2pw,   dim3(NROWS / 256),        dim3(256), 0, stream, z, z2);
        hipLaunchKernelGGL(k_exact,  dim3(NROWS / MT, NSPLIT), dim3(256), 0, stream, z, cb, c2, z2, part);
        hipLaunchKernelGGL(k_reduce, dim3(NROWS / 256),        dim3(256), 0, stream, part, widx, out);
        hipLaunchKernelGGL(k_episem, dim3(BQ * (T / 32)),      dim3(256), 0, stream, z, cb, widx, out, lossp);
        hipLaunchKernelGGL(k_epiac,  dim3(BQ * DAC * T / 1024), dim3(256), 0, stream, z, out);
        hipLaunchKernelGGL(k_lossfin, dim3(1),                 dim3(256), 0, stream, lossp, out);
    }
}

// Round 5
// 849.523 us; speedup vs baseline: 2.2897x; 2.2897x over previous
//
#include <hip/hip_runtime.h>
#include <cfloat>
#include <math.h>

// Problem constants
#define BQ 8
#define T 2048
#define D 256
#define DAC 36
#define CH 292
#define K 8192
#define NROWS (BQ*T)          // 16384
#define TAU 1.5e-4f
#define FSPLIT 4              // k-splits in fast kernel
#define NKT 16                // code-tiles (of 128) per block = 2048/128

// Output offsets (floats, reference return order)
#define OFF_IDX   (BQ*CH*T)
#define OFF_CODES (OFF_IDX + NROWS)
#define OFF_LOSS  (OFF_CODES + BQ*DAC*T)
#define OFF_ACQ   (OFF_LOSS + 1)

// ---------------- new (MFMA) ws layout, bytes ----------------
#define WN_C2    0                            // float[K]
#define WN_Z2    32768                        // float[NROWS]
#define WN_CNT   98304
#define WN_LIST  98560                        // int[NROWS]
#define WN_LOSS  164096                       // double[512]
#define WN_WIDX  168192                       // int[NROWS]
#define WN_PMX   262144                       // float4[FSPLIT*NROWS] = 1 MB
#define WN_AZ    1310720                      // ushort[16384][512] = 16 MB
#define WN_BC    18087936                     // ushort[8192][512]  = 8 MB
#define WN_NEED  26476544

// ---------------- old (fallback) ws layout ----------------
#define WS_C2    0
#define WS_Z2    32768
#define WS_PART  131072
#define WS_IDX   655360
#define WS_LOSS  720896
#define MT 32
#define KT 128
#define DC 32
#define NSPLIT 4

typedef float f32x4 __attribute__((ext_vector_type(4)));
typedef __bf16 bf16x8 __attribute__((ext_vector_type(8)));
typedef __attribute__((address_space(1))) const unsigned int gu32;
typedef __attribute__((address_space(3))) unsigned int lu32;

__device__ inline void gl_lds16(const void* gp, void* lp) {
    __builtin_amdgcn_global_load_lds((gu32*)gp, (lu32*)lp, 16, 0, 0);
}

__device__ inline unsigned short f2bf(float x) {   // RNE, finite inputs
    unsigned u = __float_as_uint(x);
    return (unsigned short)((u + 0x7fffu + ((u >> 16) & 1u)) >> 16);
}
__device__ inline float bf2f(unsigned short h) {
    return __uint_as_float(((unsigned)h) << 16);
}

__device__ inline void merge3(float& m1, float& m2, int& mi, float o1, float o2, int oi) {
    if (o1 < m1 || (o1 == m1 && oi < mi)) { m2 = fminf(m1, o2); m1 = o1; mi = oi; }
    else                                  { m2 = fminf(m2, o1); }
}

// ---- numpy pairwise-sum emulation (AVX512 W=16, n=256) ----
template <typename F>
__device__ float np_pairwise256_sq(F ld) {
    float S[2];
    #pragma unroll
    for (int h = 0; h < 2; h++) {
        int base = h * 128;
        float v[16];
        #pragma unroll
        for (int l = 0; l < 16; l++) {
            float q[8];
            #pragma unroll
            for (int j = 0; j < 8; j++) { float x = ld(base + j * 16 + l); q[j] = x * x; }
            v[l] = ((q[0] + q[1]) + (q[2] + q[3])) + ((q[4] + q[5]) + (q[6] + q[7]));
        }
        float t1[8], t2[4], t3[2];
        #pragma unroll
        for (int l = 0; l < 8; l++) t1[l] = v[l] + v[l + 8];
        #pragma unroll
        for (int l = 0; l < 4; l++) t2[l] = t1[l] + t1[l + 4];
        t3[0] = t2[0] + t2[2]; t3[1] = t2[1] + t2[3];
        S[h] = t3[0] + t3[1];
    }
    return S[0] + S[1];
}

__global__ void k_c2pw(const float* __restrict__ cb, float* __restrict__ c2) {
    int k = blockIdx.x * 256 + threadIdx.x;
    const float* row = cb + (size_t)k * D;
    c2[k] = np_pairwise256_sq([&](int d) { return row[d]; });
}

__global__ void k_z2pw(const float* __restrict__ z, float* __restrict__ z2) {
    int n = blockIdx.x * 256 + threadIdx.x;
    int b = n >> 11, t = n & 2047;
    const float* base = z + (size_t)b * CH * T + t;
    z2[n] = np_pairwise256_sq([&](int d) { return base[(size_t)d * T]; });
}

// ---------------- prep: Az[n][512] = [bf16hi(z) | bf16lo(z)] ----------------
__global__ __launch_bounds__(256) void k_prepz(const float* __restrict__ z,
                                               unsigned short* __restrict__ Az) {
    __shared__ float zt[32][260];
    const int tid = threadIdx.x;
    const int b = blockIdx.x >> 6, t0 = (blockIdx.x & 63) * 32;
    for (int i = tid; i < 2048; i += 256) {
        int d = i >> 3, tq = (i & 7) * 4;
        float4 v = *(const float4*)(z + (size_t)(b * CH + d) * T + t0 + tq);
        zt[tq + 0][d] = v.x; zt[tq + 1][d] = v.y;
        zt[tq + 2][d] = v.z; zt[tq + 3][d] = v.w;
    }
    __syncthreads();
    const int t = tid >> 3, c8 = tid & 7;
    unsigned short* rowp = Az + (size_t)(b * 2048 + t0 + t) * 512;
    #pragma unroll
    for (int li = 0; li < 8; li++) {
        int u = c8 + 8 * li;                 // 16B chunk index 0..63
        int dbase = (u & 31) * 8;
        bool lo = (u >= 32);
        float f[8];
        *(float4*)&f[0] = *(float4*)&zt[t][dbase];
        *(float4*)&f[4] = *(float4*)&zt[t][dbase + 4];
        unsigned short h[8];
        #pragma unroll
        for (int e = 0; e < 8; e++) {
            unsigned short hh = f2bf(f[e]);
            h[e] = lo ? f2bf(f[e] - bf2f(hh)) : hh;
        }
        *(uint4*)(rowp + u * 8) = *(uint4*)h;
    }
}

// ---------------- prep: Bc[k][512] = [bf16hi(c) | bf16lo(c)] ----------------
__global__ void k_prepc(const float* __restrict__ cb, unsigned short* __restrict__ Bc) {
    const int tid = threadIdx.x, w = tid >> 6, l = tid & 63;
    const int k = blockIdx.x * 4 + w;
    float4 v = *(const float4*)(cb + (size_t)k * D + l * 4);
    float fa[4] = {v.x, v.y, v.z, v.w};
    unsigned short hi[4], lo[4];
    #pragma unroll
    for (int e = 0; e < 4; e++) {
        hi[e] = f2bf(fa[e]);
        lo[e] = f2bf(fa[e] - bf2f(hi[e]));
    }
    unsigned short* rowp = Bc + (size_t)k * 512;
    *(uint2*)(rowp + l * 4)       = *(uint2*)hi;
    *(uint2*)(rowp + 256 + l * 4) = *(uint2*)lo;
}

// ---------------- MFMA fast argmin v2: 128 rows x 2048 codes per block ------
// Codes stream inside the block (16 tiles of 128); per-lane running minima in
// registers; shuffle reduction once per block; LDS double-buffered staging.
__global__ __launch_bounds__(256, 2) void k_fast(
        const unsigned short* __restrict__ Az, const unsigned short* __restrict__ Bc,
        const float* __restrict__ c2g, float4* __restrict__ pmx) {
    __shared__ unsigned char smem8[65536];   // 2 x (A 16KB | B 16KB)
    __shared__ float redm1[128], redm2[128];
    __shared__ int   redi[128];

    const int tid = threadIdx.x;
    const int w = tid >> 6, lane = tid & 63;
    const int wm = w >> 1, wn = w & 1;
    const int quad = lane >> 4, c = lane & 15, c7 = c & 7;

    const int sp = blockIdx.x >> 7;          // split 0..3
    const int nt = blockIdx.x & 127;         // row tile
    const int n0 = nt * 128;
    const int kbase = sp * 2048;

    const int srow = lane >> 3;
    const int gsw = (lane & 7) ^ (srow & 7);

    const char* Azb = (const char*)Az;
    const char* Bcb = (const char*)Bc;

    auto stage = [&](int kt, int it, int buf) {
        const int blk = it >> 2, sub = (it & 3) * 128;
        const int colA = ((blk == 1) ? 512 : 0) + sub;   // A: [zh | zl | zh]
        const int colB = ((blk == 2) ? 512 : 0) + sub;   // B: [ch | ch | cl]
        const int k0 = kbase + kt * 128;
        unsigned char* base = smem8 + buf * 32768;
        #pragma unroll
        for (int q = 0; q < 4; q++) {
            const int seg = w * 4 + q;
            gl_lds16(Azb + (size_t)(n0 + seg * 8 + srow) * 1024 + colA + gsw * 16,
                     base + seg * 1024);
            gl_lds16(Bcb + (size_t)(k0 + seg * 8 + srow) * 1024 + colB + gsw * 16,
                     base + 16384 + seg * 1024);
        }
    };

    float bm1[16], bm2[16]; int bid[16];
    #pragma unroll
    for (int sl = 0; sl < 16; sl++) { bm1[sl] = FLT_MAX; bm2[sl] = FLT_MAX; bid[sl] = 0x7fffffff; }

    int cur = 0;
    stage(0, 0, 0);
    for (int kt = 0; kt < NKT; kt++) {
        f32x4 acc[4][4];
        #pragma unroll
        for (int i = 0; i < 4; i++)
            #pragma unroll
            for (int j = 0; j < 4; j++) acc[i][j] = (f32x4)0.0f;

        for (int it = 0; it < 12; it++) {
            __syncthreads();                  // buf[cur] staging complete
            int nit = it + 1, nkt = kt;
            if (nit == 12) { nit = 0; nkt++; }
            if (nkt < NKT) stage(nkt, nit, cur ^ 1);   // prefetch overlaps MFMA
            unsigned char* base = smem8 + cur * 32768;
            #pragma unroll
            for (int s2 = 0; s2 < 2; s2++) {
                const int sw = ((((s2 << 2) | quad) ^ c7) << 4);
                bf16x8 af[4], bfr[4];
                #pragma unroll
                for (int i = 0; i < 4; i++)
                    af[i] = *(const bf16x8*)(base + (wm * 64 + i * 16 + c) * 128 + sw);
                #pragma unroll
                for (int j = 0; j < 4; j++)
                    bfr[j] = *(const bf16x8*)(base + 16384 + (wn * 64 + j * 16 + c) * 128 + sw);
                #pragma unroll
                for (int i = 0; i < 4; i++)
                    #pragma unroll
                    for (int j = 0; j < 4; j++)
                        acc[i][j] = __builtin_amdgcn_mfma_f32_16x16x32_bf16(af[i], bfr[j], acc[i][j], 0, 0, 0);
            }
            cur ^= 1;
        }
        // cheap per-tile register epilogue (k ascending -> strict <, first idx)
        const int ktk = kbase + kt * 128;
        #pragma unroll
        for (int j = 0; j < 4; j++) {
            const int kk = ktk + wn * 64 + j * 16 + c;
            const float c2v = c2g[kk];
            #pragma unroll
            for (int i = 0; i < 4; i++)
                #pragma unroll
                for (int r = 0; r < 4; r++) {
                    float sc = fmaf(-2.0f, acc[i][j][r], c2v);
                    int sl = i * 4 + r;
                    if (sc < bm1[sl]) { bm2[sl] = bm1[sl]; bm1[sl] = sc; bid[sl] = kk; }
                    else if (sc < bm2[sl]) bm2[sl] = sc;
                }
        }
    }

    // once-per-block reduction: butterfly over the 16 c-lanes (same quad)
    #pragma unroll
    for (int mask = 1; mask <= 8; mask <<= 1)
        #pragma unroll
        for (int sl = 0; sl < 16; sl++) {
            float o1 = __shfl_xor(bm1[sl], mask, 64);
            float o2 = __shfl_xor(bm2[sl], mask, 64);
            int   oi = __shfl_xor(bid[sl], mask, 64);
            merge3(bm1[sl], bm2[sl], bid[sl], o1, o2, oi);
        }
    if (c == 0 && wn == 0) {
        #pragma unroll
        for (int i = 0; i < 4; i++)
            #pragma unroll
            for (int r = 0; r < 4; r++) {
                int ml = wm * 64 + i * 16 + quad * 4 + r, sl = i * 4 + r;
                redm1[ml] = bm1[sl]; redm2[ml] = bm2[sl]; redi[ml] = bid[sl];
            }
    }
    __syncthreads();
    if (c == 0 && wn == 1) {
        #pragma unroll
        for (int i = 0; i < 4; i++)
            #pragma unroll
            for (int r = 0; r < 4; r++) {
                int ml = wm * 64 + i * 16 + quad * 4 + r, sl = i * 4 + r;
                merge3(bm1[sl], bm2[sl], bid[sl], redm1[ml], redm2[ml], redi[ml]);
                pmx[(size_t)sp * NROWS + n0 + ml] =
                    make_float4(bm1[sl], bm2[sl], __int_as_float(bid[sl]), 0.f);
            }
    }
}

// ---------------- reduce 4 k-splits; flag ambiguous rows ----------------
__global__ void k_reduce2(const float4* __restrict__ pmx, int* __restrict__ widx,
                          int* __restrict__ cnt, int* __restrict__ list,
                          float* __restrict__ out) {
    int n = blockIdx.x * 256 + threadIdx.x;
    float a1 = FLT_MAX, a2 = FLT_MAX; int ai = 0x7fffffff;
    #pragma unroll
    for (int s = 0; s < FSPLIT; s++) {
        float4 p = pmx[(size_t)s * NROWS + n];
        merge3(a1, a2, ai, p.x, p.y, __float_as_int(p.z));
    }
    widx[n] = ai;
    out[OFF_IDX + n] = (float)ai;
    if (a2 - a1 < TAU) { int pos = atomicAdd(cnt, 1); list[pos] = n; }
}

// ---------------- exact np-pipeline rescue for flagged rows ----------------
__global__ __launch_bounds__(256) void k_rescue2(
        const float* __restrict__ z, const float* __restrict__ cb,
        const float* __restrict__ c2, const float* __restrict__ z2,
        const int* __restrict__ cnt, const int* __restrict__ list,
        int* __restrict__ widx, float* __restrict__ out) {
    __shared__ float zrow[D];
    __shared__ float rv[256];
    __shared__ int   ri[256];
    __shared__ int   srown;
    const int tid = threadIdx.x;
    const int cntv = *cnt;
    for (int i = blockIdx.x; i < cntv; i += 256) {
        if (tid == 0) srown = list[i];
        __syncthreads();
        const int n = srown;
        const int bb = n >> 11, tt = n & 2047;
        zrow[tid] = z[(size_t)(bb * CH + tid) * T + tt];
        const float z2n = z2[n];
        __syncthreads();
        float bm = FLT_MAX; int bi = 0x7fffffff;
        for (int g = 0; g < 8; g++) {         // 4 interleaved k-chains, k ascending
            const int kq0 = tid + 256 * (4 * g);
            const float4* cr0 = (const float4*)(cb + (size_t)(kq0 + 0)   * D);
            const float4* cr1 = (const float4*)(cb + (size_t)(kq0 + 256) * D);
            const float4* cr2 = (const float4*)(cb + (size_t)(kq0 + 512) * D);
            const float4* cr3 = (const float4*)(cb + (size_t)(kq0 + 768) * D);
            float e0 = 0.f, e1 = 0.f, e2 = 0.f, e3 = 0.f;
            #pragma unroll 8
            for (int d4 = 0; d4 < 64; d4++) {
                float4 a = cr0[d4], b = cr1[d4], cc = cr2[d4], dd = cr3[d4];
                float z0 = zrow[d4 * 4 + 0], z1 = zrow[d4 * 4 + 1];
                float z2v = zrow[d4 * 4 + 2], z3 = zrow[d4 * 4 + 3];
                e0 = fmaf(z0, a.x, e0);  e0 = fmaf(z1, a.y, e0);
                e0 = fmaf(z2v, a.z, e0); e0 = fmaf(z3, a.w, e0);
                e1 = fmaf(z0, b.x, e1);  e1 = fmaf(z1, b.y, e1);
                e1 = fmaf(z2v, b.z, e1); e1 = fmaf(z3, b.w, e1);
                e2 = fmaf(z0, cc.x, e2);  e2 = fmaf(z1, cc.y, e2);
                e2 = fmaf(z2v, cc.z, e2); e2 = fmaf(z3, cc.w, e2);
                e3 = fmaf(z0, dd.x, e3);  e3 = fmaf(z1, dd.y, e3);
                e3 = fmaf(z2v, dd.z, e3); e3 = fmaf(z3, dd.w, e3);
            }
            float s0 = (z2n - 2.0f * e0) + c2[kq0 + 0];
            float s1 = (z2n - 2.0f * e1) + c2[kq0 + 256];
            float s2 = (z2n - 2.0f * e2) + c2[kq0 + 512];
            float s3 = (z2n - 2.0f * e3) + c2[kq0 + 768];
            if (s0 < bm) { bm = s0; bi = kq0 + 0; }      // ascending order kept
            if (s1 < bm) { bm = s1; bi = kq0 + 256; }
            if (s2 < bm) { bm = s2; bi = kq0 + 512; }
            if (s3 < bm) { bm = s3; bi = kq0 + 768; }
        }
        rv[tid] = bm; ri[tid] = bi;
        __syncthreads();
        for (int s = 128; s > 0; s >>= 1) {
            if (tid < s) {
                float ov = rv[tid + s]; int oi = ri[tid + s];
                if (ov < rv[tid] || (ov == rv[tid] && oi < ri[tid])) { rv[tid] = ov; ri[tid] = oi; }
            }
            __syncthreads();
        }
        if (tid == 0) { widx[n] = ri[0]; out[OFF_IDX + n] = (float)ri[0]; }
        __syncthreads();
    }
}

// ---------------- fallback exact fp32 GEMM-argmin (Round-3, passing) --------
__global__ __launch_bounds__(256) void k_exact(
        const float* __restrict__ z, const float* __restrict__ cb,
        const float* __restrict__ c2, const float* __restrict__ z2,
        float2* __restrict__ part) {
    __shared__ float zs[D][MT];
    __shared__ float cs[DC][KT + 4];
    const int tid = threadIdx.x;
    const int tx = tid & 31, ty = tid >> 5;
    const int n0 = blockIdx.x * MT;
    const int bb = n0 >> 11, t0 = n0 & 2047;
    const int kbase = blockIdx.y * (K / NSPLIT);
    for (int i = tid; i < D * (MT / 4); i += 256) {
        int d = i >> 3, tg = i & 7;
        float4 v = *(const float4*)(z + ((size_t)(bb * CH + d)) * T + t0 + tg * 4);
        *(float4*)&zs[d][tg * 4] = v;
    }
    float z2r[4];
    #pragma unroll
    for (int i = 0; i < 4; i++) z2r[i] = z2[n0 + ty * 4 + i];
    float m1[4]; int bi[4];
    #pragma unroll
    for (int i = 0; i < 4; i++) { m1[i] = FLT_MAX; bi[i] = 0x7fffffff; }
    for (int ktt = 0; ktt < K / NSPLIT; ktt += KT) {
        const int k0 = kbase + ktt;
        float acc[4][4] = {};
        for (int dc = 0; dc < D; dc += DC) {
            __syncthreads();
            {
                int kl = tid & 127, half = tid >> 7;
                const float4* src = (const float4*)(cb + (size_t)(k0 + kl) * D + dc + half * 16);
                #pragma unroll
                for (int j = 0; j < 4; j++) {
                    float4 v = src[j];
                    int dl = half * 16 + j * 4;
                    cs[dl + 0][kl] = v.x; cs[dl + 1][kl] = v.y;
                    cs[dl + 2][kl] = v.z; cs[dl + 3][kl] = v.w;
                }
            }
            __syncthreads();
            #pragma unroll 8
            for (int d = 0; d < DC; d++) {
                const float4 zf = *(const float4*)&zs[dc + d][ty * 4];
                const float4 cf = *(const float4*)&cs[d][tx * 4];
                const float za[4] = {zf.x, zf.y, zf.z, zf.w};
                const float ca[4] = {cf.x, cf.y, cf.z, cf.w};
                #pragma unroll
                for (int i = 0; i < 4; i++)
                    #pragma unroll
                    for (int j = 0; j < 4; j++)
                        acc[i][j] = fmaf(za[i], ca[j], acc[i][j]);
            }
        }
        #pragma unroll
        for (int j = 0; j < 4; j++) {
            int kk = k0 + tx * 4 + j;
            float c2v = c2[kk];
            #pragma unroll
            for (int i = 0; i < 4; i++) {
                float tpre = z2r[i] - 2.0f * acc[i][j];
                float s = tpre + c2v;
                if (s < m1[i]) { m1[i] = s; bi[i] = kk; }
            }
        }
    }
    __syncthreads();
    float* rm1 = (float*)zs;
    int*   rix = (int*)(rm1 + MT * 32);
    #pragma unroll
    for (int i = 0; i < 4; i++) {
        int slot = (ty * 4 + i) * 32 + tx;
        rm1[slot] = m1[i]; rix[slot] = bi[i];
    }
    __syncthreads();
    if (tid < MT) {
        float a1 = FLT_MAX; int ai = 0x7fffffff;
        for (int t = 0; t < 32; t++) {
            float b1 = rm1[tid * 32 + t]; int bidx = rix[tid * 32 + t];
            if (b1 < a1 || (b1 == a1 && bidx < ai)) { a1 = b1; ai = bidx; }
        }
        part[(size_t)(n0 + tid) * NSPLIT + blockIdx.y] = make_float2(a1, __int_as_float(ai));
    }
}

__global__ void k_reduce(const float2* __restrict__ part, int* __restrict__ widx,
                         float* __restrict__ out) {
    int n = blockIdx.x * 256 + threadIdx.x;
    float a1 = FLT_MAX; int ai = 0x7fffffff;
    #pragma unroll
    for (int s = 0; s < NSPLIT; s++) {
        float2 p = part[(size_t)n * NSPLIT + s];
        float b1 = p.x; int bidx = __float_as_int(p.y);
        if (b1 < a1 || (b1 == a1 && bidx < ai)) { a1 = b1; ai = bidx; }
    }
    widx[n] = ai;
    out[OFF_IDX + n] = (float)ai;
}

// ------------- epilogue: gather z_q + loss partials ----------------
__global__ __launch_bounds__(256) void k_episem(
        const float* __restrict__ z, const float* __restrict__ cb,
        const int* __restrict__ widx, float* __restrict__ out, double* __restrict__ lossp) {
    __shared__ int qidx[32];
    __shared__ float qs[32][260];
    __shared__ double wsum[4];
    const int tid = threadIdx.x;
    const int bb = blockIdx.x >> 6;
    const int t0 = (blockIdx.x & 63) * 32;
    if (tid < 32) qidx[tid] = widx[bb * T + t0 + tid];
    __syncthreads();
    for (int i = tid; i < 32 * 64; i += 256) {
        int tl = i >> 6, lanee = i & 63;
        float4 v = *(const float4*)(cb + (size_t)qidx[tl] * D + lanee * 4);
        *(float4*)&qs[tl][lanee * 4] = v;
    }
    __syncthreads();
    double ls = 0.0;
    for (int it = 0; it < 32; it++) {
        int d = it * 8 + (tid >> 5);
        int tl = tid & 31;
        size_t ga = ((size_t)(bb * CH + d)) * T + t0 + tl;
        float q = qs[tl][d];
        float e = q - z[ga];
        out[ga] = q;
        ls += (double)e * (double)e;
    }
    #pragma unroll
    for (int off = 32; off; off >>= 1) ls += __shfl_down(ls, off, 64);
    if ((tid & 63) == 0) wsum[tid >> 6] = ls;
    __syncthreads();
    if (tid == 0) lossp[blockIdx.x] = wsum[0] + wsum[1] + wsum[2] + wsum[3];
}

// ------------- epilogue: ac path ----------------
__global__ void k_epiac(const float* __restrict__ z, float* __restrict__ out) {
    int i = (blockIdx.x * 256 + threadIdx.x) * 4;
    if (i >= BQ * DAC * T) return;
    int b = i / (DAC * T);
    int r = i % (DAC * T);
    int d = r / T, t = r % T;
    size_t zoff = ((size_t)(b * CH + 256 + d)) * T + t;
    float4 v = *(const float4*)(z + zoff);
    float r0, r1, r2, r3;
    {
        float t0 = (float)tanh((double)v.x); r0 = rintf(t0 * 10.0f);
        float t1 = (float)tanh((double)v.y); r1 = rintf(t1 * 10.0f);
        float t2 = (float)tanh((double)v.z); r2 = rintf(t2 * 10.0f);
        float t3 = (float)tanh((double)v.w); r3 = rintf(t3 * 10.0f);
    }
    *(float4*)(out + zoff) = make_float4(r0, r1, r2, r3);
    size_t co = OFF_CODES + (size_t)(b * DAC + d) * T + t;
    *(float4*)(out + co) = make_float4(r0 + 10.0f, r1 + 10.0f, r2 + 10.0f, r3 + 10.0f);
    size_t ao = OFF_ACQ + (size_t)(b * DAC + d) * T + t;
    out[ao + 0] = r0; out[ao + 1] = r1; out[ao + 2] = r2; out[ao + 3] = r3;
}

__global__ void k_lossfin(const double* __restrict__ lossp, float* __restrict__ out) {
    __shared__ double sm[256];
    int tid = threadIdx.x;
    sm[tid] = lossp[tid] + lossp[tid + 256];
    __syncthreads();
    for (int off = 128; off; off >>= 1) {
        if (tid < off) sm[tid] += sm[tid + off];
        __syncthreads();
    }
    if (tid == 0) out[OFF_LOSS] = (float)(1.1 * sm[0] / (double)(BQ * D * T));
}

extern "C" void kernel_launch(void* const* d_in, const int* in_sizes, int n_in,
                              void* d_out, int out_size, void* d_ws, size_t ws_size,
                              hipStream_t stream) {
    const float* z  = (const float*)d_in[0];
    const float* cb = (const float*)d_in[1];
    float* out = (float*)d_out;
    char* ws = (char*)d_ws;

    if (ws_size >= (size_t)WN_NEED) {
        float*  c2    = (float*)(ws + WN_C2);
        float*  z2    = (float*)(ws + WN_Z2);
        int*    cnt   = (int*)(ws + WN_CNT);
        int*    list  = (int*)(ws + WN_LIST);
        double* lossp = (double*)(ws + WN_LOSS);
        int*    widx  = (int*)(ws + WN_WIDX);
        float4* pmx   = (float4*)(ws + WN_PMX);
        unsigned short* Az = (unsigned short*)(ws + WN_AZ);
        unsigned short* Bc = (unsigned short*)(ws + WN_BC);

        hipMemsetAsync(cnt, 0, 4, stream);
        hipLaunchKernelGGL(k_prepc,   dim3(K / 4),       dim3(256), 0, stream, cb, Bc);
        hipLaunchKernelGGL(k_prepz,   dim3(512),         dim3(256), 0, stream, z, Az);
        hipLaunchKernelGGL(k_c2pw,    dim3(K / 256),     dim3(256), 0, stream, cb, c2);
        hipLaunchKernelGGL(k_z2pw,    dim3(NROWS / 256), dim3(256), 0, stream, z, z2);
        hipLaunchKernelGGL(k_fast,    dim3(128 * FSPLIT), dim3(256), 0, stream, Az, Bc, c2, pmx);
        hipLaunchKernelGGL(k_reduce2, dim3(NROWS / 256), dim3(256), 0, stream, pmx, widx, cnt, list, out);
        hipLaunchKernelGGL(k_rescue2, dim3(256),         dim3(256), 0, stream, z, cb, c2, z2, cnt, list, widx, out);
        hipLaunchKernelGGL(k_episem,  dim3(BQ * (T / 32)), dim3(256), 0, stream, z, cb, widx, out, lossp);
        hipLaunchKernelGGL(k_epiac,   dim3(BQ * DAC * T / 1024), dim3(256), 0, stream, z, out);
        hipLaunchKernelGGL(k_lossfin, dim3(1),           dim3(256), 0, stream, lossp, out);
    } else {
        float*  c2    = (float*)(ws + WS_C2);
        float*  z2    = (float*)(ws + WS_Z2);
        float2* part  = (float2*)(ws + WS_PART);
        int*    widx  = (int*)(ws + WS_IDX);
        double* lossp = (double*)(ws + WS_LOSS);
        hipLaunchKernelGGL(k_c2pw,   dim3(K / 256),            dim3(256), 0, stream, cb, c2);
        hipLaunchKernelGGL(k_z2pw,   dim3(NROWS / 256),        dim3(256), 0, stream, z, z2);
        hipLaunchKernelGGL(k_exact,  dim3(NROWS / MT, NSPLIT), dim3(256), 0, stream, z, cb, c2, z2, part);
        hipLaunchKernelGGL(k_reduce, dim3(NROWS / 256),        dim3(256), 0, stream, part, widx, out);
        hipLaunchKernelGGL(k_episem, dim3(BQ * (T / 32)),      dim3(256), 0, stream, z, cb, widx, out, lossp);
        hipLaunchKernelGGL(k_epiac,  dim3(BQ * DAC * T / 1024), dim3(256), 0, stream, z, out);
        hipLaunchKernelGGL(k_lossfin, dim3(1),                 dim3(256), 0, stream, lossp, out);
    }
}